// Round 14
// baseline (2906.781 us; speedup 1.0000x reference)
//
#include <hip/hip_runtime.h>
#include <hip/hip_bf16.h>
#include <math.h>

#define BS 8192
#define HID 256
#define SPB1 8

// ---- workspace layout (float element offsets) ----
#define WT1_OFF 0
#define WT2_OFF 65536
#define WT3_OFF 131072
#define WT0_OFF 196608
#define S_OFF   204800
#define C_OFF   (S_OFF + 4 * BS * HID)
#define G_OFF   (C_OFF + 4 * BS * HID)
#define WBT_OFF (G_OFF + BS * 16)
// WBT region: brick-swizzled W: 3 lay x 2 (hi,lo) x 8 nt x 16 kb x 64 lanes x 8 shorts

typedef __attribute__((ext_vector_type(8))) short bf16x8;
typedef __attribute__((ext_vector_type(16))) float f32x16;
#define MFMA32(A, B, C) __builtin_amdgcn_mfma_f32_32x32x16_bf16(A, B, C, 0, 0, 0)

__device__ __forceinline__ ushort bf16_rne(float x) {
    unsigned u = __float_as_uint(x);
    unsigned r = u + 0x7FFFu + ((u >> 16) & 1u);
    return (ushort)(r >> 16);
}
__device__ __forceinline__ void bsplit(float x, ushort& hi, ushort& lo) {
    hi = bf16_rne(x);
    float hf = __uint_as_float(((unsigned)hi) << 16);
    lo = bf16_rne(x - hf);
}

// packed split via v_cvt_pk_bf16_f32 (gfx950)
__device__ __forceinline__ uint pk2(float a, float b) {
    __hip_bfloat162 h = __float22bfloat162_rn(float2{a, b});
    uint u; __builtin_memcpy(&u, &h, 4); return u;
}
__device__ __forceinline__ void split2(float a, float b, uint& hp, uint& lp) {
    hp = pk2(a, b);
    float ha = __uint_as_float(hp << 16);
    float hb = __uint_as_float(hp & 0xFFFF0000u);
    lp = pk2(a - ha, b - hb);
}
__device__ __forceinline__ void split4v(const float* v, uint2& H, uint2& L) {
    split2(v[0], v[1], H.x, L.x);
    split2(v[2], v[3], H.y, L.y);
}

__device__ __forceinline__ void silu_derivs(float a, float& h, float& sp, float& fpp) {
    float sig = 1.0f / (1.0f + __expf(-a));
    float om  = 1.0f - sig;
    h   = a * sig;
    sp  = sig * (1.0f + a * om);                       // silu'
    fpp = sig * om * (2.0f + a * (1.0f - 2.0f * sig)); // silu''
}

// ---------------- kernel 0: weight transposes + bf16 brick swizzle ----------------
__global__ void k_transpose(const float* __restrict__ W0, const float* __restrict__ W1,
                            const float* __restrict__ W2, const float* __restrict__ W3,
                            float* __restrict__ ws) {
    float* WT1 = ws + WT1_OFF;
    float* WT2 = ws + WT2_OFF;
    float* WT3 = ws + WT3_OFF;
    float* WT0 = ws + WT0_OFF;
    ushort* WBT = (ushort*)(ws + WBT_OFF);
    int o = blockIdx.x;      // 0..255 (output col)
    int t = threadIdx.x;     // 0..255 (input row k)
    int which = blockIdx.y;  // 0..3
    if (which < 3) {
        const float* W = (which == 0) ? W1 : (which == 1) ? W2 : W3;
        float* WT = (which == 0) ? WT1 : (which == 1) ? WT2 : WT3;
        float v = W[t * 256 + o];
        WT[o * 256 + t] = v;
        ushort h, l;
        bsplit(v, h, l);
        const int ntg = o >> 5, ln0 = o & 31;
        const int kb = t >> 4, hfb = (t >> 3) & 1, j = t & 7;
        const int laneidx = ln0 + 32 * hfb;
        WBT[(((which * 2 + 0) * 128) + ntg * 16 + kb) * 512 + laneidx * 8 + j] = h;
        WBT[(((which * 2 + 1) * 128) + ntg * 16 + kb) * 512 + laneidx * 8 + j] = l;
    } else if (t < 32) {
        WT0[o * 32 + t] = W0[t * 256 + o]; // WT0[i][k] = W0[k][i]
    }
}

// ---------------- kernel 1: forward + backward (8 samples/block) ----------------
__device__ __forceinline__ void fwd_layer(int L, int t, int m0,
        const float (*Hin)[SPB1], float (*Hout)[SPB1],
        const float* __restrict__ W, const float* __restrict__ b,
        float* __restrict__ f2, float* __restrict__ S)
{
    float acc[SPB1];
    #pragma unroll
    for (int s = 0; s < SPB1; ++s) acc[s] = b[t];
    const float4* H4 = (const float4*)&Hin[0][0];
    #pragma unroll 8
    for (int i = 0; i < 256; ++i) {
        float w = W[i * 256 + t];
        float4 h0 = H4[i * 2 + 0];
        float4 h1 = H4[i * 2 + 1];
        acc[0] += h0.x * w; acc[1] += h0.y * w; acc[2] += h0.z * w; acc[3] += h0.w * w;
        acc[4] += h1.x * w; acc[5] += h1.y * w; acc[6] += h1.z * w; acc[7] += h1.w * w;
    }
    #pragma unroll
    for (int s = 0; s < SPB1; ++s) {
        float h, sp, fpp;
        silu_derivs(acc[s], h, sp, fpp);
        Hout[t][s] = h;
        S[(L * BS + m0 + s) * HID + t] = sp;
        f2[s] = fpp;
    }
}

__device__ __forceinline__ void bwd_layer(int L, int t, int m0,
        const float (*Din)[SPB1], float (*Dout)[SPB1],
        const float* __restrict__ WT,
        const float* __restrict__ f2,
        const float* __restrict__ S, float* __restrict__ C)
{
    float acc[SPB1];
    #pragma unroll
    for (int s = 0; s < SPB1; ++s) acc[s] = 0.0f;
    const float4* D4 = (const float4*)&Din[0][0];
    #pragma unroll 8
    for (int o = 0; o < 256; ++o) {
        float w = WT[o * 256 + t];
        float4 d0 = D4[o * 2 + 0];
        float4 d1 = D4[o * 2 + 1];
        acc[0] += d0.x * w; acc[1] += d0.y * w; acc[2] += d0.z * w; acc[3] += d0.w * w;
        acc[4] += d1.x * w; acc[5] += d1.y * w; acc[6] += d1.z * w; acc[7] += d1.w * w;
    }
    #pragma unroll
    for (int s = 0; s < SPB1; ++s) {
        float dh = acc[s];
        float sl = S[(L * BS + m0 + s) * HID + t];
        C[(L * BS + m0 + s) * HID + t] = dh * f2[s];
        Dout[t][s] = dh * sl;  // delta_a
    }
}

__global__ __launch_bounds__(256) void k_stage1(
    const float* __restrict__ z,
    const float* __restrict__ W0, const float* __restrict__ b0,
    const float* __restrict__ W1, const float* __restrict__ b1,
    const float* __restrict__ W2, const float* __restrict__ b2,
    const float* __restrict__ W3, const float* __restrict__ b3,
    const float* __restrict__ W4,
    const float* __restrict__ WT0, const float* __restrict__ WT1,
    const float* __restrict__ WT2, const float* __restrict__ WT3,
    float* __restrict__ S, float* __restrict__ C, float* __restrict__ G)
{
    __shared__ __align__(16) float Zt[SPB1][32];
    __shared__ __align__(16) float Ha[256][SPB1];
    __shared__ __align__(16) float Hb[256][SPB1];
    const int t  = threadIdx.x;
    const int m0 = blockIdx.x * SPB1;
    float f2a[3][SPB1];   // silu'' layers 0..2: same-thread produce/consume

    Zt[t >> 5][t & 31] = z[(m0 + (t >> 5)) * 32 + (t & 31)];
    __syncthreads();

    // ---- layer 1: a1 = z @ W0 + b0 ----
    {
        float acc[SPB1];
        #pragma unroll
        for (int s = 0; s < SPB1; ++s) acc[s] = b0[t];
        #pragma unroll 8
        for (int i = 0; i < 32; ++i) {
            float w = W0[i * 256 + t];
            #pragma unroll
            for (int s = 0; s < SPB1; ++s) acc[s] += Zt[s][i] * w;
        }
        #pragma unroll
        for (int s = 0; s < SPB1; ++s) {
            float h, sp, fpp;
            silu_derivs(acc[s], h, sp, fpp);
            Ha[t][s] = h;
            S[(0 * BS + m0 + s) * HID + t] = sp;
            f2a[0][s] = fpp;
        }
    }
    __syncthreads();
    fwd_layer(1, t, m0, Ha, Hb, W1, b1, f2a[1], S);  // h2
    __syncthreads();
    fwd_layer(2, t, m0, Hb, Ha, W2, b2, f2a[2], S);  // h3
    __syncthreads();
    // ---- layer 4 + start of backward ----
    {
        float acc[SPB1];
        #pragma unroll
        for (int s = 0; s < SPB1; ++s) acc[s] = b3[t];
        const float4* H4 = (const float4*)&Ha[0][0];
        #pragma unroll 8
        for (int i = 0; i < 256; ++i) {
            float w = W3[i * 256 + t];
            float4 h0 = H4[i * 2 + 0];
            float4 h1 = H4[i * 2 + 1];
            acc[0] += h0.x * w; acc[1] += h0.y * w; acc[2] += h0.z * w; acc[3] += h0.w * w;
            acc[4] += h1.x * w; acc[5] += h1.y * w; acc[6] += h1.z * w; acc[7] += h1.w * w;
        }
        float w4 = W4[t];
        #pragma unroll
        for (int s = 0; s < SPB1; ++s) {
            float h, sp, fpp;
            silu_derivs(acc[s], h, sp, fpp);
            Hb[t][s] = w4 * sp;                          // delta_a4
            C[(3 * BS + m0 + s) * HID + t] = w4 * fpp;   // c4
        }
    }
    __syncthreads();
    bwd_layer(2, t, m0, Hb, Ha, WT3, f2a[2], S, C);  // delta_a3 in Ha
    __syncthreads();
    bwd_layer(1, t, m0, Ha, Hb, WT2, f2a[1], S, C);  // delta_a2 in Hb
    __syncthreads();
    bwd_layer(0, t, m0, Hb, Ha, WT1, f2a[0], S, C);  // delta_a1 in Ha
    __syncthreads();
    // ---- gradient: g[k] = sum_i W0[k][i] * delta_a1[i] ----
    {
        const int k = t & 31, sh = t >> 5;
        float acc = 0.0f;
        #pragma unroll 4
        for (int i = 0; i < 256; ++i) acc += WT0[i * 32 + k] * Ha[i][sh];
        if (k < 16) G[(m0 + sh) * 16 + k] = acc;
    }
}

// ---------------- kernel 2: 8-wave 32x32 MFMA tangent propagation ----------------
// 1 sample/block, 512 threads = 8 waves; wave w owns ONE 32-col n-tile.
// R14: identical to R12 (best verified config: single-buffered slots, C/S
// prefetch, ks=0,1 brick hoist) but __launch_bounds__(512,8): R12's natural
// VGPR allocation is exactly 64 (measured, unpressured under a 128 cap), and
// LDS 4x39936 = 159.7 KB <= 160 KB, so 4 blocks/CU are resource-feasible.
// (512,4) only guarantees 2 blocks; measured OccupancyPercent ~26% suggests
// the scheduler placed ~1. (512,8) requests the full 8 waves/EU.
#define RS2 72    // shorts per slot row (144 B)
#define STP 68    // floats per staging row (stride ≡ 4 mod 32 banks)

__global__ __launch_bounds__(512, 8) void k_stage2(
    const float* __restrict__ z,
    const float* __restrict__ W0,
    const ushort* __restrict__ WBT,
    const float* __restrict__ S, const float* __restrict__ C, const float* __restrict__ G,
    float* __restrict__ out)
{
    // slots: 0=ASh 1=ASl 2=ACh 3=ACl 4=TPh 5=TPl  (each 32 x RS2 shorts)
    __shared__ __align__(16) ushort SMEM[6 * 32 * RS2];   // 27648 B
    __shared__ __align__(16) float stg[32 * STP];         // 8704 B
    __shared__ float HCl[32][16];
    __shared__ float Msys[16][17];
    __shared__ float vvs[16];
    // total ~39.6 KB -> 4 blocks/CU at (512,8)

    const int t    = threadIdx.x;   // 0..511
    const int m    = blockIdx.x;
    const int lane = t & 63;
    const int w    = t >> 6;        // wave 0..7
    const int ln   = lane & 31;
    const int hf   = lane >> 5;
    const int er   = t >> 4;        // epilogue row 0..31
    const int ej   = (t & 15) * 4;  // epilogue col offset 0,4,..60

#define SLOT(a) (&SMEM[(a) * 32 * RS2])

    f32x16 Tacc;   // this wave's T columns (32w + ln), MFMA C-layout
    f32x16 Tnxt;
    f32x16 Dacc;
    #pragma unroll
    for (int r = 0; r < 16; ++r) { Tacc[r] = 0.0f; Tnxt[r] = 0.0f; Dacc[r] = 0.0f; }

    // prefetch C/S for (lay=0, p=0)
    float4 cc = *(const float4*)&C[(0 * BS + m) * HID + ej];
    float4 sv = *(const float4*)&S[(0 * BS + m) * HID + ej];

    for (int lay = 0; lay < 4; ++lay) {
        for (int p = 0; p < 4; ++p) {
            // ---- issue next-phase C/S loads (consumed next phase after 2 barriers)
            float4 cn, sn;
            const int nlay = (p < 3) ? lay : lay + 1;
            const int np   = (p < 3) ? p + 1 : 0;
            if (nlay < 4) {
                cn = *(const float4*)&C[(nlay * BS + m) * HID + np * 64 + ej];
                if (nlay < 3)
                    sn = *(const float4*)&S[(nlay * BS + m) * HID + np * 64 + ej];
            }

            // ---- hoisted brick loads for ks=0,1 (latency covered by epilogue) ----
            bf16x8 Bh01[2], Bl01[2];
            if (lay < 3) {
                #pragma unroll
                for (int ks = 0; ks < 2; ++ks) {
                    const int kb = p * 4 + ks;
                    Bh01[ks] = *(const bf16x8*)&WBT[
                        (((lay * 2 + 0) * 128) + w * 16 + kb) * 512 + lane * 8];
                    Bl01[ks] = *(const bf16x8*)&WBT[
                        (((lay * 2 + 1) * 128) + w * 16 + kb) * 512 + lane * 8];
                }
            }

            // ---------- epilogue: 512 threads x 4 elements ----------
            {
                float tv[4], tmp[4];
                if (lay == 0) {
                    *(float4*)tv = *(const float4*)&W0[er * HID + p * 64 + ej];
                } else {
                    *(float4*)tv = *(const float4*)&stg[er * STP + ej];
                }
                uint2 H, L;
                tmp[0] = cc.x * tv[0]; tmp[1] = cc.y * tv[1];
                tmp[2] = cc.z * tv[2]; tmp[3] = cc.w * tv[3];
                split4v(tmp, H, L);
                *(uint2*)(SLOT(2) + er * RS2 + ej) = H;
                *(uint2*)(SLOT(3) + er * RS2 + ej) = L;
                if (lay < 3) {
                    tmp[0] = sv.x * tv[0]; tmp[1] = sv.y * tv[1];
                    tmp[2] = sv.z * tv[2]; tmp[3] = sv.w * tv[3];
                    split4v(tmp, H, L);
                    *(uint2*)(SLOT(0) + er * RS2 + ej) = H;
                    *(uint2*)(SLOT(1) + er * RS2 + ej) = L;
                }
                if (er >= 16) {   // waves 4..7 — wave-uniform branch
                    split4v(tv, H, L);
                    *(uint2*)(SLOT(4) + (er - 16) * RS2 + ej) = H;
                    *(uint2*)(SLOT(5) + (er - 16) * RS2 + ej) = L;
                }
            }
            __syncthreads();

            // ---------- contraction: waves 0..3, wave w takes K-chunk w ----------
            if (w < 4) {
                const int ko = w * 16 + hf * 8;
                bf16x8 Bph = *(const bf16x8*)(SLOT(4) + ln * RS2 + ko);
                bf16x8 Bpl = *(const bf16x8*)(SLOT(5) + ln * RS2 + ko);
                bf16x8 Ah = *(const bf16x8*)(SLOT(2) + ln * RS2 + ko);
                bf16x8 Al = *(const bf16x8*)(SLOT(3) + ln * RS2 + ko);
                Dacc = MFMA32(Ah, Bph, MFMA32(Al, Bph, MFMA32(Ah, Bpl, Dacc)));
            }

            // ---------- GEMM: all 8 waves, wave w owns n-tile w ----------
            if (lay < 3) {
                #pragma unroll
                for (int ks = 0; ks < 4; ++ks) {
                    const int ko = ks * 16 + hf * 8;
                    const int kb = p * 4 + ks;
                    bf16x8 Ah = *(const bf16x8*)(SLOT(0) + ln * RS2 + ko);
                    bf16x8 Al = *(const bf16x8*)(SLOT(1) + ln * RS2 + ko);
                    bf16x8 Bh, Bl;
                    if (ks < 2) { Bh = Bh01[ks]; Bl = Bl01[ks]; }
                    else {
                        Bh = *(const bf16x8*)&WBT[
                            (((lay * 2 + 0) * 128) + w * 16 + kb) * 512 + lane * 8];
                        Bl = *(const bf16x8*)&WBT[
                            (((lay * 2 + 1) * 128) + w * 16 + kb) * 512 + lane * 8];
                    }
                    Tnxt = MFMA32(Ah, Bh,
                           MFMA32(Al, Bh,
                           MFMA32(Ah, Bl, Tnxt)));
                }
            }

            // ---------- staging dump for the NEXT phase ----------
            {
                bool dumpNow = false, fromN = false;
                if (p < 3) { dumpNow = (lay > 0) && ((w >> 1) == p + 1); }
                else       { dumpNow = (lay < 3) && (w < 2); fromN = true; }
                if (dumpNow) {
                    #pragma unroll
                    for (int r = 0; r < 16; ++r) {
                        const int row = (r & 3) + 8 * (r >> 2) + 4 * hf;
                        stg[row * STP + (w & 1) * 32 + ln] = fromN ? Tnxt[r] : Tacc[r];
                    }
                }
            }
            __syncthreads();

            // ---- rotate prefetched C/S ----
            if (nlay < 4) {
                cc = cn;
                if (nlay < 3) sv = sn;
            }
        } // p

        // ---------- layer end: Tacc <- Tnxt (registers only) ----------
        if (lay < 3) {
            Tacc = Tnxt;
            #pragma unroll
            for (int r = 0; r < 16; ++r) Tnxt[r] = 0.0f;
        }
    } // lay

    // ---------- reduce Hessian partials (overlay on SMEM; only 16 valid cols) ---
    float* Dred = (float*)SMEM;   // [4][32][16] = 8 KB
    if (w < 4) {
        #pragma unroll
        for (int r = 0; r < 16; ++r) {
            const int row = (r & 3) + 8 * (r >> 2) + 4 * hf;
            if (ln < 16) Dred[(w * 32 + row) * 16 + ln] = Dacc[r];
        }
    }
    __syncthreads();

    // ---------- wave-0 reduce + solve ----------
    if (w == 0) {
        for (int idx = lane; idx < 512; idx += 64) {
            const int row = idx >> 4, j = idx & 15;
            HCl[row][j] = Dred[(0 * 32 + row) * 16 + j] + Dred[(1 * 32 + row) * 16 + j]
                        + Dred[(2 * 32 + row) * 16 + j] + Dred[(3 * 32 + row) * 16 + j];
        }

        float* M = &Msys[0][0];   // [16][17]
        float vr = 0.0f;
        if (lane < 16) {
            vr = z[m * 32 + 16 + lane];
            vvs[lane] = vr;
        }
        if (lane < 16) {
            #pragma unroll
            for (int j = 0; j < 16; ++j)
                M[lane * 17 + j] = HCl[16 + lane][j] + (lane == j ? 0.2f : 0.0f);
            float r = G[m * 16 + lane];
            #pragma unroll
            for (int j = 0; j < 16; ++j)
                r -= HCl[j][lane] * vvs[j];
            M[lane * 17 + 16] = r;
        }
        // Gauss-Jordan with partial pivoting (wave-synchronous)
        for (int k2 = 0; k2 < 16; ++k2) {
            float val = (lane < 16 && lane >= k2) ? fabsf(M[lane * 17 + k2]) : -1.0f;
            int idx = lane;
            #pragma unroll
            for (int off = 8; off > 0; off >>= 1) {
                float ov = __shfl_xor(val, off, 64);
                int oi = __shfl_xor(idx, off, 64);
                if (ov > val) { val = ov; idx = oi; }
            }
            const int p2 = __shfl(idx, 0, 64);
            if (p2 != k2 && lane < 17) {
                float tmp = M[k2 * 17 + lane];
                M[k2 * 17 + lane] = M[p2 * 17 + lane];
                M[p2 * 17 + lane] = tmp;
            }
            if (lane < 16) {
                const float f = (lane == k2) ? 0.0f : M[lane * 17 + k2] / M[k2 * 17 + k2];
                #pragma unroll
                for (int j = 0; j < 17; ++j)
                    M[lane * 17 + j] -= f * M[k2 * 17 + j];
            }
        }
        if (lane < 16) {
            out[m * 32 + lane]      = vr;
            out[m * 32 + 16 + lane] = M[lane * 17 + 16] / M[lane * 17 + lane];
        }
    }
#undef SLOT
}

extern "C" void kernel_launch(void* const* d_in, const int* in_sizes, int n_in,
                              void* d_out, int out_size, void* d_ws, size_t ws_size,
                              hipStream_t stream) {
    const float* z  = (const float*)d_in[1];
    const float* W0 = (const float*)d_in[2];
    const float* b0 = (const float*)d_in[3];
    const float* W1 = (const float*)d_in[4];
    const float* b1 = (const float*)d_in[5];
    const float* W2 = (const float*)d_in[6];
    const float* b2 = (const float*)d_in[7];
    const float* W3 = (const float*)d_in[8];
    const float* b3 = (const float*)d_in[9];
    const float* W4 = (const float*)d_in[10];
    float* out = (float*)d_out;
    float* ws  = (float*)d_ws;

    float* WT1 = ws + WT1_OFF;
    float* WT2 = ws + WT2_OFF;
    float* WT3 = ws + WT3_OFF;
    float* WT0 = ws + WT0_OFF;
    float* S   = ws + S_OFF;
    float* C   = ws + C_OFF;
    float* G   = ws + G_OFF;
    const ushort* WBT = (const ushort*)(ws + WBT_OFF);

    k_transpose<<<dim3(256, 4), 256, 0, stream>>>(W0, W1, W2, W3, ws);
    k_stage1<<<BS / SPB1, 256, 0, stream>>>(z, W0, b0, W1, b1, W2, b2, W3, b3, W4,
                                            WT0, WT1, WT2, WT3, S, C, G);
    k_stage2<<<BS, 512, 0, stream>>>(z, W0, WBT, S, C, G, out);
}

// Round 15
// 838.638 us; speedup vs baseline: 3.4661x; 3.4661x over previous
//
#include <hip/hip_runtime.h>
#include <hip/hip_bf16.h>
#include <math.h>

#define BS 8192
#define HID 256
#define SPB1 8

// ---- workspace layout (float element offsets) ----
#define WT1_OFF 0
#define WT2_OFF 65536
#define WT3_OFF 131072
#define WT0_OFF 196608
#define S_OFF   204800
#define C_OFF   (S_OFF + 4 * BS * HID)
#define G_OFF   (C_OFF + 4 * BS * HID)
#define WBT_OFF (G_OFF + BS * 16)
// WBT region: brick-swizzled W: 3 lay x 2 (hi,lo) x 8 nt x 16 kb x 64 lanes x 8 shorts

typedef __attribute__((ext_vector_type(8))) short bf16x8;
typedef __attribute__((ext_vector_type(16))) float f32x16;
#define MFMA32(A, B, C) __builtin_amdgcn_mfma_f32_32x32x16_bf16(A, B, C, 0, 0, 0)

__device__ __forceinline__ ushort bf16_rne(float x) {
    unsigned u = __float_as_uint(x);
    unsigned r = u + 0x7FFFu + ((u >> 16) & 1u);
    return (ushort)(r >> 16);
}
__device__ __forceinline__ void bsplit(float x, ushort& hi, ushort& lo) {
    hi = bf16_rne(x);
    float hf = __uint_as_float(((unsigned)hi) << 16);
    lo = bf16_rne(x - hf);
}

// packed split via v_cvt_pk_bf16_f32 (gfx950)
__device__ __forceinline__ uint pk2(float a, float b) {
    __hip_bfloat162 h = __float22bfloat162_rn(float2{a, b});
    uint u; __builtin_memcpy(&u, &h, 4); return u;
}
__device__ __forceinline__ void split2(float a, float b, uint& hp, uint& lp) {
    hp = pk2(a, b);
    float ha = __uint_as_float(hp << 16);
    float hb = __uint_as_float(hp & 0xFFFF0000u);
    lp = pk2(a - ha, b - hb);
}
__device__ __forceinline__ void split8v(const float* v, uint4& H, uint4& L) {
    split2(v[0], v[1], H.x, L.x);
    split2(v[2], v[3], H.y, L.y);
    split2(v[4], v[5], H.z, L.z);
    split2(v[6], v[7], H.w, L.w);
}

__device__ __forceinline__ void silu_derivs(float a, float& h, float& sp, float& fpp) {
    float sig = 1.0f / (1.0f + __expf(-a));
    float om  = 1.0f - sig;
    h   = a * sig;
    sp  = sig * (1.0f + a * om);                       // silu'
    fpp = sig * om * (2.0f + a * (1.0f - 2.0f * sig)); // silu''
}

// ---------------- kernel 0: weight transposes + bf16 brick swizzle ----------------
__global__ void k_transpose(const float* __restrict__ W0, const float* __restrict__ W1,
                            const float* __restrict__ W2, const float* __restrict__ W3,
                            float* __restrict__ ws) {
    float* WT1 = ws + WT1_OFF;
    float* WT2 = ws + WT2_OFF;
    float* WT3 = ws + WT3_OFF;
    float* WT0 = ws + WT0_OFF;
    ushort* WBT = (ushort*)(ws + WBT_OFF);
    int o = blockIdx.x;      // 0..255 (output col)
    int t = threadIdx.x;     // 0..255 (input row k)
    int which = blockIdx.y;  // 0..3
    if (which < 3) {
        const float* W = (which == 0) ? W1 : (which == 1) ? W2 : W3;
        float* WT = (which == 0) ? WT1 : (which == 1) ? WT2 : WT3;
        float v = W[t * 256 + o];
        WT[o * 256 + t] = v;
        ushort h, l;
        bsplit(v, h, l);
        const int ntg = o >> 5, ln0 = o & 31;
        const int kb = t >> 4, hfb = (t >> 3) & 1, j = t & 7;
        const int laneidx = ln0 + 32 * hfb;
        WBT[(((which * 2 + 0) * 128) + ntg * 16 + kb) * 512 + laneidx * 8 + j] = h;
        WBT[(((which * 2 + 1) * 128) + ntg * 16 + kb) * 512 + laneidx * 8 + j] = l;
    } else if (t < 32) {
        WT0[o * 32 + t] = W0[t * 256 + o]; // WT0[i][k] = W0[k][i]
    }
}

// ---------------- kernel 1: forward + backward (8 samples/block) ----------------
__device__ __forceinline__ void fwd_layer(int L, int t, int m0,
        const float (*Hin)[SPB1], float (*Hout)[SPB1],
        const float* __restrict__ W, const float* __restrict__ b,
        float* __restrict__ f2, float* __restrict__ S)
{
    float acc[SPB1];
    #pragma unroll
    for (int s = 0; s < SPB1; ++s) acc[s] = b[t];
    const float4* H4 = (const float4*)&Hin[0][0];
    #pragma unroll 8
    for (int i = 0; i < 256; ++i) {
        float w = W[i * 256 + t];
        float4 h0 = H4[i * 2 + 0];
        float4 h1 = H4[i * 2 + 1];
        acc[0] += h0.x * w; acc[1] += h0.y * w; acc[2] += h0.z * w; acc[3] += h0.w * w;
        acc[4] += h1.x * w; acc[5] += h1.y * w; acc[6] += h1.z * w; acc[7] += h1.w * w;
    }
    #pragma unroll
    for (int s = 0; s < SPB1; ++s) {
        float h, sp, fpp;
        silu_derivs(acc[s], h, sp, fpp);
        Hout[t][s] = h;
        S[(L * BS + m0 + s) * HID + t] = sp;
        f2[s] = fpp;
    }
}

__device__ __forceinline__ void bwd_layer(int L, int t, int m0,
        const float (*Din)[SPB1], float (*Dout)[SPB1],
        const float* __restrict__ WT,
        const float* __restrict__ f2,
        const float* __restrict__ S, float* __restrict__ C)
{
    float acc[SPB1];
    #pragma unroll
    for (int s = 0; s < SPB1; ++s) acc[s] = 0.0f;
    const float4* D4 = (const float4*)&Din[0][0];
    #pragma unroll 8
    for (int o = 0; o < 256; ++o) {
        float w = WT[o * 256 + t];
        float4 d0 = D4[o * 2 + 0];
        float4 d1 = D4[o * 2 + 1];
        acc[0] += d0.x * w; acc[1] += d0.y * w; acc[2] += d0.z * w; acc[3] += d0.w * w;
        acc[4] += d1.x * w; acc[5] += d1.y * w; acc[6] += d1.z * w; acc[7] += d1.w * w;
    }
    #pragma unroll
    for (int s = 0; s < SPB1; ++s) {
        float dh = acc[s];
        float sl = S[(L * BS + m0 + s) * HID + t];
        C[(L * BS + m0 + s) * HID + t] = dh * f2[s];
        Dout[t][s] = dh * sl;  // delta_a
    }
}

__global__ __launch_bounds__(256) void k_stage1(
    const float* __restrict__ z,
    const float* __restrict__ W0, const float* __restrict__ b0,
    const float* __restrict__ W1, const float* __restrict__ b1,
    const float* __restrict__ W2, const float* __restrict__ b2,
    const float* __restrict__ W3, const float* __restrict__ b3,
    const float* __restrict__ W4,
    const float* __restrict__ WT0, const float* __restrict__ WT1,
    const float* __restrict__ WT2, const float* __restrict__ WT3,
    float* __restrict__ S, float* __restrict__ C, float* __restrict__ G)
{
    __shared__ __align__(16) float Zt[SPB1][32];
    __shared__ __align__(16) float Ha[256][SPB1];
    __shared__ __align__(16) float Hb[256][SPB1];
    const int t  = threadIdx.x;
    const int m0 = blockIdx.x * SPB1;
    float f2a[3][SPB1];   // silu'' layers 0..2: same-thread produce/consume

    Zt[t >> 5][t & 31] = z[(m0 + (t >> 5)) * 32 + (t & 31)];
    __syncthreads();

    // ---- layer 1: a1 = z @ W0 + b0 ----
    {
        float acc[SPB1];
        #pragma unroll
        for (int s = 0; s < SPB1; ++s) acc[s] = b0[t];
        #pragma unroll 8
        for (int i = 0; i < 32; ++i) {
            float w = W0[i * 256 + t];
            #pragma unroll
            for (int s = 0; s < SPB1; ++s) acc[s] += Zt[s][i] * w;
        }
        #pragma unroll
        for (int s = 0; s < SPB1; ++s) {
            float h, sp, fpp;
            silu_derivs(acc[s], h, sp, fpp);
            Ha[t][s] = h;
            S[(0 * BS + m0 + s) * HID + t] = sp;
            f2a[0][s] = fpp;
        }
    }
    __syncthreads();
    fwd_layer(1, t, m0, Ha, Hb, W1, b1, f2a[1], S);  // h2
    __syncthreads();
    fwd_layer(2, t, m0, Hb, Ha, W2, b2, f2a[2], S);  // h3
    __syncthreads();
    // ---- layer 4 + start of backward ----
    {
        float acc[SPB1];
        #pragma unroll
        for (int s = 0; s < SPB1; ++s) acc[s] = b3[t];
        const float4* H4 = (const float4*)&Ha[0][0];
        #pragma unroll 8
        for (int i = 0; i < 256; ++i) {
            float w = W3[i * 256 + t];
            float4 h0 = H4[i * 2 + 0];
            float4 h1 = H4[i * 2 + 1];
            acc[0] += h0.x * w; acc[1] += h0.y * w; acc[2] += h0.z * w; acc[3] += h0.w * w;
            acc[4] += h1.x * w; acc[5] += h1.y * w; acc[6] += h1.z * w; acc[7] += h1.w * w;
        }
        float w4 = W4[t];
        #pragma unroll
        for (int s = 0; s < SPB1; ++s) {
            float h, sp, fpp;
            silu_derivs(acc[s], h, sp, fpp);
            Hb[t][s] = w4 * sp;                          // delta_a4
            C[(3 * BS + m0 + s) * HID + t] = w4 * fpp;   // c4
        }
    }
    __syncthreads();
    bwd_layer(2, t, m0, Hb, Ha, WT3, f2a[2], S, C);  // delta_a3 in Ha
    __syncthreads();
    bwd_layer(1, t, m0, Ha, Hb, WT2, f2a[1], S, C);  // delta_a2 in Hb
    __syncthreads();
    bwd_layer(0, t, m0, Hb, Ha, WT1, f2a[0], S, C);  // delta_a1 in Ha
    __syncthreads();
    // ---- gradient: g[k] = sum_i W0[k][i] * delta_a1[i] ----
    {
        const int k = t & 31, sh = t >> 5;
        float acc = 0.0f;
        #pragma unroll 4
        for (int i = 0; i < 256; ++i) acc += WT0[i * 32 + k] * Ha[i][sh];
        if (k < 16) G[(m0 + sh) * 16 + k] = acc;
    }
}

// ---------------- kernel 2: 8-wave 32x32 MFMA, PH=128 (2 phases/layer) ----------
// 1 sample/block, 512 threads = 8 waves; wave w owns ONE 32-col n-tile.
// R15: R12 structure but 128 cols per phase: phases 16->8, barriers 32->16,
// contraction uses ALL 8 waves (8 K-chunks of 16). Register law (R8/R9/R11/R14):
// true demand ~112 regs incl. accumulators -> 4 waves/SIMD max; (512,4) is the
// only clean point. Brick hoist dropped (-16 regs) to fit the wider epilogue +
// 32-reg C/S prefetch under the 128 cap.
#define RSW 136   // shorts per slot row (272 B, ≡4 dwords mod 32 banks)
#define STW 132   // floats per stg row (≡4 mod 32)

__global__ __launch_bounds__(512, 4) void k_stage2(
    const float* __restrict__ z,
    const float* __restrict__ W0,
    const ushort* __restrict__ WBT,
    const float* __restrict__ S, const float* __restrict__ C, const float* __restrict__ G,
    float* __restrict__ out)
{
    // slots: 0=ASh 1=ASl 2=ACh 3=ACl 4=TPh 5=TPl  (each 32 x RSW shorts)
    __shared__ __align__(16) ushort SMEM[6 * 32 * RSW];   // 52224 B
    __shared__ __align__(16) float stg[32 * STW];         // 16896 B
    __shared__ float HCl[32][16];
    __shared__ float Msys[16][17];
    __shared__ float vvs[16];
    // total ~73.4 KB -> 2 blocks/CU

    const int t    = threadIdx.x;   // 0..511
    const int m    = blockIdx.x;
    const int lane = t & 63;
    const int w    = t >> 6;        // wave 0..7
    const int ln   = lane & 31;
    const int hf   = lane >> 5;
    const int er   = t >> 4;        // epilogue row 0..31
    const int ej   = (t & 15) * 8;  // epilogue col offset 0,8,..120

#define SLOT(a) (&SMEM[(a) * 32 * RSW])

    f32x16 Tacc;   // this wave's T columns (32w + ln), MFMA C-layout
    f32x16 Tnxt;
    f32x16 Dacc;
    #pragma unroll
    for (int r = 0; r < 16; ++r) { Tacc[r] = 0.0f; Tnxt[r] = 0.0f; Dacc[r] = 0.0f; }

    // prefetch C/S for (lay=0, p=0)
    float4 cc0, cc1, ss0, ss1;
    {
        const float* Cp = &C[(0 * BS + m) * HID + ej];
        const float* Sp = &S[(0 * BS + m) * HID + ej];
        cc0 = *(const float4*)Cp; cc1 = *(const float4*)(Cp + 4);
        ss0 = *(const float4*)Sp; ss1 = *(const float4*)(Sp + 4);
    }

    for (int lay = 0; lay < 4; ++lay) {
        for (int p = 0; p < 2; ++p) {
            // ---- issue next-phase C/S loads (consumed next phase) ----
            float4 cn0, cn1, sn0, sn1;
            const int nlay = (p < 1) ? lay : lay + 1;
            const int np   = (p < 1) ? 1 : 0;
            if (nlay < 4) {
                const float* Cp = &C[(nlay * BS + m) * HID + np * 128 + ej];
                cn0 = *(const float4*)Cp; cn1 = *(const float4*)(Cp + 4);
                if (nlay < 3) {
                    const float* Sp = &S[(nlay * BS + m) * HID + np * 128 + ej];
                    sn0 = *(const float4*)Sp; sn1 = *(const float4*)(Sp + 4);
                }
            }

            // ---------- epilogue: 512 threads x 8 elements ----------
            {
                float tv[8], tmp[8];
                if (lay == 0) {
                    const float* Wp = &W0[er * HID + p * 128 + ej];
                    *(float4*)&tv[0] = *(const float4*)Wp;
                    *(float4*)&tv[4] = *(const float4*)(Wp + 4);
                } else {
                    *(float4*)&tv[0] = *(const float4*)&stg[er * STW + ej];
                    *(float4*)&tv[4] = *(const float4*)&stg[er * STW + ej + 4];
                }
                uint4 H, L;
                tmp[0] = cc0.x * tv[0]; tmp[1] = cc0.y * tv[1];
                tmp[2] = cc0.z * tv[2]; tmp[3] = cc0.w * tv[3];
                tmp[4] = cc1.x * tv[4]; tmp[5] = cc1.y * tv[5];
                tmp[6] = cc1.z * tv[6]; tmp[7] = cc1.w * tv[7];
                split8v(tmp, H, L);
                *(uint4*)(SLOT(2) + er * RSW + ej) = H;
                *(uint4*)(SLOT(3) + er * RSW + ej) = L;
                if (lay < 3) {
                    tmp[0] = ss0.x * tv[0]; tmp[1] = ss0.y * tv[1];
                    tmp[2] = ss0.z * tv[2]; tmp[3] = ss0.w * tv[3];
                    tmp[4] = ss1.x * tv[4]; tmp[5] = ss1.y * tv[5];
                    tmp[6] = ss1.z * tv[6]; tmp[7] = ss1.w * tv[7];
                    split8v(tmp, H, L);
                    *(uint4*)(SLOT(0) + er * RSW + ej) = H;
                    *(uint4*)(SLOT(1) + er * RSW + ej) = L;
                }
                if (er >= 16) {   // waves 4..7 — wave-uniform branch
                    split8v(tv, H, L);
                    *(uint4*)(SLOT(4) + (er - 16) * RSW + ej) = H;
                    *(uint4*)(SLOT(5) + (er - 16) * RSW + ej) = L;
                }
            }
            __syncthreads();

            // ---------- contraction: ALL 8 waves, wave w takes K-chunk w ----------
            {
                const int ko = w * 16 + hf * 8;
                bf16x8 Bph = *(const bf16x8*)(SLOT(4) + ln * RSW + ko);
                bf16x8 Bpl = *(const bf16x8*)(SLOT(5) + ln * RSW + ko);
                bf16x8 Ah = *(const bf16x8*)(SLOT(2) + ln * RSW + ko);
                bf16x8 Al = *(const bf16x8*)(SLOT(3) + ln * RSW + ko);
                Dacc = MFMA32(Ah, Bph, MFMA32(Al, Bph, MFMA32(Ah, Bpl, Dacc)));
            }

            // ---------- GEMM: all 8 waves, wave w owns n-tile w, 8 K-chunks -------
            if (lay < 3) {
                #pragma unroll
                for (int ks = 0; ks < 8; ++ks) {
                    const int ko = ks * 16 + hf * 8;
                    const int kb = p * 8 + ks;
                    bf16x8 Ah = *(const bf16x8*)(SLOT(0) + ln * RSW + ko);
                    bf16x8 Al = *(const bf16x8*)(SLOT(1) + ln * RSW + ko);
                    bf16x8 Bh = *(const bf16x8*)&WBT[
                        (((lay * 2 + 0) * 128) + w * 16 + kb) * 512 + lane * 8];
                    bf16x8 Bl = *(const bf16x8*)&WBT[
                        (((lay * 2 + 1) * 128) + w * 16 + kb) * 512 + lane * 8];
                    Tnxt = MFMA32(Ah, Bh,
                           MFMA32(Al, Bh,
                           MFMA32(Ah, Bl, Tnxt)));
                }
            }

            // ---------- staging dump for the NEXT phase ----------
            if (p == 0) {
                if (lay > 0 && w >= 4) {   // next phase = cols 128..255 (Tacc)
                    #pragma unroll
                    for (int r = 0; r < 16; ++r) {
                        const int row = (r & 3) + 8 * (r >> 2) + 4 * hf;
                        stg[row * STW + (w - 4) * 32 + ln] = Tacc[r];
                    }
                }
            } else {
                if (lay < 3 && w < 4) {    // next layer cols 0..127 (Tnxt)
                    #pragma unroll
                    for (int r = 0; r < 16; ++r) {
                        const int row = (r & 3) + 8 * (r >> 2) + 4 * hf;
                        stg[row * STW + w * 32 + ln] = Tnxt[r];
                    }
                }
            }
            __syncthreads();

            // ---- rotate prefetched C/S ----
            if (nlay < 4) {
                cc0 = cn0; cc1 = cn1;
                if (nlay < 3) { ss0 = sn0; ss1 = sn1; }
            }
        } // p

        // ---------- layer end: Tacc <- Tnxt (registers only) ----------
        if (lay < 3) {
            Tacc = Tnxt;
            #pragma unroll
            for (int r = 0; r < 16; ++r) Tnxt[r] = 0.0f;
        }
    } // lay

    // ---------- reduce Hessian partials (overlay on SMEM; 16 valid cols) ----
    float* Dred = (float*)SMEM;   // [8][32][16] = 16 KB <= 52 KB
    {
        #pragma unroll
        for (int r = 0; r < 16; ++r) {
            const int row = (r & 3) + 8 * (r >> 2) + 4 * hf;
            if (ln < 16) Dred[(w * 32 + row) * 16 + ln] = Dacc[r];
        }
    }
    __syncthreads();

    // ---------- wave-0 reduce + solve ----------
    if (w == 0) {
        for (int idx = lane; idx < 512; idx += 64) {
            const int row = idx >> 4, j = idx & 15;
            float v = 0.0f;
            #pragma unroll
            for (int wv = 0; wv < 8; ++wv) v += Dred[(wv * 32 + row) * 16 + j];
            HCl[row][j] = v;
        }

        float* M = &Msys[0][0];   // [16][17]
        float vr = 0.0f;
        if (lane < 16) {
            vr = z[m * 32 + 16 + lane];
            vvs[lane] = vr;
        }
        if (lane < 16) {
            #pragma unroll
            for (int j = 0; j < 16; ++j)
                M[lane * 17 + j] = HCl[16 + lane][j] + (lane == j ? 0.2f : 0.0f);
            float r = G[m * 16 + lane];
            #pragma unroll
            for (int j = 0; j < 16; ++j)
                r -= HCl[j][lane] * vvs[j];
            M[lane * 17 + 16] = r;
        }
        // Gauss-Jordan with partial pivoting (wave-synchronous)
        for (int k2 = 0; k2 < 16; ++k2) {
            float val = (lane < 16 && lane >= k2) ? fabsf(M[lane * 17 + k2]) : -1.0f;
            int idx = lane;
            #pragma unroll
            for (int off = 8; off > 0; off >>= 1) {
                float ov = __shfl_xor(val, off, 64);
                int oi = __shfl_xor(idx, off, 64);
                if (ov > val) { val = ov; idx = oi; }
            }
            const int p2 = __shfl(idx, 0, 64);
            if (p2 != k2 && lane < 17) {
                float tmp = M[k2 * 17 + lane];
                M[k2 * 17 + lane] = M[p2 * 17 + lane];
                M[p2 * 17 + lane] = tmp;
            }
            if (lane < 16) {
                const float f = (lane == k2) ? 0.0f : M[lane * 17 + k2] / M[k2 * 17 + k2];
                #pragma unroll
                for (int j = 0; j < 17; ++j)
                    M[lane * 17 + j] -= f * M[k2 * 17 + j];
            }
        }
        if (lane < 16) {
            out[m * 32 + lane]      = vr;
            out[m * 32 + 16 + lane] = M[lane * 17 + 16] / M[lane * 17 + lane];
        }
    }
#undef SLOT
}

extern "C" void kernel_launch(void* const* d_in, const int* in_sizes, int n_in,
                              void* d_out, int out_size, void* d_ws, size_t ws_size,
                              hipStream_t stream) {
    const float* z  = (const float*)d_in[1];
    const float* W0 = (const float*)d_in[2];
    const float* b0 = (const float*)d_in[3];
    const float* W1 = (const float*)d_in[4];
    const float* b1 = (const float*)d_in[5];
    const float* W2 = (const float*)d_in[6];
    const float* b2 = (const float*)d_in[7];
    const float* W3 = (const float*)d_in[8];
    const float* b3 = (const float*)d_in[9];
    const float* W4 = (const float*)d_in[10];
    float* out = (float*)d_out;
    float* ws  = (float*)d_ws;

    float* WT1 = ws + WT1_OFF;
    float* WT2 = ws + WT2_OFF;
    float* WT3 = ws + WT3_OFF;
    float* WT0 = ws + WT0_OFF;
    float* S   = ws + S_OFF;
    float* C   = ws + C_OFF;
    float* G   = ws + G_OFF;
    const ushort* WBT = (const ushort*)(ws + WBT_OFF);

    k_transpose<<<dim3(256, 4), 256, 0, stream>>>(W0, W1, W2, W3, ws);
    k_stage1<<<BS / SPB1, 256, 0, stream>>>(z, W0, b0, W1, b1, W2, b2, W3, b3, W4,
                                            WT0, WT1, WT2, WT3, S, C, G);
    k_stage2<<<BS, 512, 0, stream>>>(z, W0, WBT, S, C, G, out);
}

// Round 16
// 830.123 us; speedup vs baseline: 3.5016x; 1.0103x over previous
//
#include <hip/hip_runtime.h>
#include <hip/hip_bf16.h>
#include <math.h>

#define BS 8192
#define HID 256
#define SPB1 16

// ---- workspace layout (float element offsets) ----
#define WT1_OFF 0
#define WT2_OFF 65536
#define WT3_OFF 131072
#define WT0_OFF 196608
#define S_OFF   204800
#define C_OFF   (S_OFF + 4 * BS * HID)
#define G_OFF   (C_OFF + 4 * BS * HID)
#define WBT_OFF (G_OFF + BS * 16)
// WBT region: brick-swizzled W: 3 lay x 2 (hi,lo) x 8 nt x 16 kb x 64 lanes x 8 shorts

typedef __attribute__((ext_vector_type(8))) short bf16x8;
typedef __attribute__((ext_vector_type(16))) float f32x16;
#define MFMA32(A, B, C) __builtin_amdgcn_mfma_f32_32x32x16_bf16(A, B, C, 0, 0, 0)

__device__ __forceinline__ ushort bf16_rne(float x) {
    unsigned u = __float_as_uint(x);
    unsigned r = u + 0x7FFFu + ((u >> 16) & 1u);
    return (ushort)(r >> 16);
}
__device__ __forceinline__ void bsplit(float x, ushort& hi, ushort& lo) {
    hi = bf16_rne(x);
    float hf = __uint_as_float(((unsigned)hi) << 16);
    lo = bf16_rne(x - hf);
}

// packed split via v_cvt_pk_bf16_f32 (gfx950)
__device__ __forceinline__ uint pk2(float a, float b) {
    __hip_bfloat162 h = __float22bfloat162_rn(float2{a, b});
    uint u; __builtin_memcpy(&u, &h, 4); return u;
}
__device__ __forceinline__ void split2(float a, float b, uint& hp, uint& lp) {
    hp = pk2(a, b);
    float ha = __uint_as_float(hp << 16);
    float hb = __uint_as_float(hp & 0xFFFF0000u);
    lp = pk2(a - ha, b - hb);
}
__device__ __forceinline__ void split8v(const float* v, uint4& H, uint4& L) {
    split2(v[0], v[1], H.x, L.x);
    split2(v[2], v[3], H.y, L.y);
    split2(v[4], v[5], H.z, L.z);
    split2(v[6], v[7], H.w, L.w);
}

__device__ __forceinline__ void silu_derivs(float a, float& h, float& sp, float& fpp) {
    float sig = 1.0f / (1.0f + __expf(-a));
    float om  = 1.0f - sig;
    h   = a * sig;
    sp  = sig * (1.0f + a * om);                       // silu'
    fpp = sig * om * (2.0f + a * (1.0f - 2.0f * sig)); // silu''
}

// ---------------- kernel 0: weight transposes + bf16 brick swizzle ----------------
__global__ void k_transpose(const float* __restrict__ W0, const float* __restrict__ W1,
                            const float* __restrict__ W2, const float* __restrict__ W3,
                            float* __restrict__ ws) {
    float* WT1 = ws + WT1_OFF;
    float* WT2 = ws + WT2_OFF;
    float* WT3 = ws + WT3_OFF;
    float* WT0 = ws + WT0_OFF;
    ushort* WBT = (ushort*)(ws + WBT_OFF);
    int o = blockIdx.x;      // 0..255 (output col)
    int t = threadIdx.x;     // 0..255 (input row k)
    int which = blockIdx.y;  // 0..3
    if (which < 3) {
        const float* W = (which == 0) ? W1 : (which == 1) ? W2 : W3;
        float* WT = (which == 0) ? WT1 : (which == 1) ? WT2 : WT3;
        float v = W[t * 256 + o];
        WT[o * 256 + t] = v;
        ushort h, l;
        bsplit(v, h, l);
        const int ntg = o >> 5, ln0 = o & 31;
        const int kb = t >> 4, hfb = (t >> 3) & 1, j = t & 7;
        const int laneidx = ln0 + 32 * hfb;
        WBT[(((which * 2 + 0) * 128) + ntg * 16 + kb) * 512 + laneidx * 8 + j] = h;
        WBT[(((which * 2 + 1) * 128) + ntg * 16 + kb) * 512 + laneidx * 8 + j] = l;
    } else if (t < 32) {
        WT0[o * 32 + t] = W0[t * 256 + o]; // WT0[i][k] = W0[k][i]
    }
}

// ---------------- kernel 1: forward + backward (16 samples/block) ----------------
// SPB1=16 halves W-load count per FMA (stage1 is load-latency bound).
// silu'' routed through C (fwd writes raw fpp; bwd same-thread RMW C=dh*fpp)
// to avoid the 48-reg f2a private array that spilled in R3.
__device__ __forceinline__ void fwd16(int L, int t, int m0,
        const float (*Hin)[SPB1], float (*Hout)[SPB1],
        const float* __restrict__ W, const float* __restrict__ b,
        float* __restrict__ S, float* __restrict__ C)
{
    float acc[SPB1];
    #pragma unroll
    for (int s = 0; s < SPB1; ++s) acc[s] = b[t];
    const float4* H4 = (const float4*)&Hin[0][0];
    #pragma unroll 4
    for (int i = 0; i < 256; ++i) {
        float w = W[i * 256 + t];
        #pragma unroll
        for (int q = 0; q < 4; ++q) {
            float4 h = H4[i * 4 + q];
            acc[q * 4 + 0] += h.x * w; acc[q * 4 + 1] += h.y * w;
            acc[q * 4 + 2] += h.z * w; acc[q * 4 + 3] += h.w * w;
        }
    }
    #pragma unroll
    for (int s = 0; s < SPB1; ++s) {
        float h, sp, fpp;
        silu_derivs(acc[s], h, sp, fpp);
        Hout[t][s] = h;
        S[(L * BS + m0 + s) * HID + t] = sp;
        C[(L * BS + m0 + s) * HID + t] = fpp;   // raw silu''; bwd scales it
    }
}

__device__ __forceinline__ void bwd16(int L, int t, int m0,
        const float (*Din)[SPB1], float (*Dout)[SPB1],
        const float* __restrict__ WT,
        const float* __restrict__ S, float* __restrict__ C)
{
    float acc[SPB1];
    #pragma unroll
    for (int s = 0; s < SPB1; ++s) acc[s] = 0.0f;
    const float4* D4 = (const float4*)&Din[0][0];
    #pragma unroll 4
    for (int o = 0; o < 256; ++o) {
        float w = WT[o * 256 + t];
        #pragma unroll
        for (int q = 0; q < 4; ++q) {
            float4 d = D4[o * 4 + q];
            acc[q * 4 + 0] += d.x * w; acc[q * 4 + 1] += d.y * w;
            acc[q * 4 + 2] += d.z * w; acc[q * 4 + 3] += d.w * w;
        }
    }
    #pragma unroll
    for (int s = 0; s < SPB1; ++s) {
        const int idx = (L * BS + m0 + s) * HID + t;
        float dh = acc[s];
        float fpp = C[idx];          // raw silu'' written by fwd (same thread)
        C[idx] = dh * fpp;
        Dout[t][s] = dh * S[idx];    // delta_a
    }
}

__global__ __launch_bounds__(256) void k_stage1(
    const float* __restrict__ z,
    const float* __restrict__ W0, const float* __restrict__ b0,
    const float* __restrict__ W1, const float* __restrict__ b1,
    const float* __restrict__ W2, const float* __restrict__ b2,
    const float* __restrict__ W3, const float* __restrict__ b3,
    const float* __restrict__ W4,
    const float* __restrict__ WT0, const float* __restrict__ WT1,
    const float* __restrict__ WT2, const float* __restrict__ WT3,
    float* __restrict__ S, float* __restrict__ C, float* __restrict__ G)
{
    __shared__ __align__(16) float Zt[32][SPB1];     // [i][s]
    __shared__ __align__(16) float Ha[256][SPB1];
    __shared__ __align__(16) float Hb[256][SPB1];
    const int t  = threadIdx.x;
    const int m0 = blockIdx.x * SPB1;

    for (int e = t; e < 32 * SPB1; e += 256) {
        int i = e >> 4, s = e & 15;
        Zt[i][s] = z[(m0 + s) * 32 + i];
    }
    __syncthreads();

    // ---- layer 1: a1 = z @ W0 + b0 ----
    {
        float acc[SPB1];
        #pragma unroll
        for (int s = 0; s < SPB1; ++s) acc[s] = b0[t];
        const float4* Z4 = (const float4*)&Zt[0][0];
        #pragma unroll 4
        for (int i = 0; i < 32; ++i) {
            float w = W0[i * 256 + t];
            #pragma unroll
            for (int q = 0; q < 4; ++q) {
                float4 zz = Z4[i * 4 + q];
                acc[q * 4 + 0] += zz.x * w; acc[q * 4 + 1] += zz.y * w;
                acc[q * 4 + 2] += zz.z * w; acc[q * 4 + 3] += zz.w * w;
            }
        }
        #pragma unroll
        for (int s = 0; s < SPB1; ++s) {
            float h, sp, fpp;
            silu_derivs(acc[s], h, sp, fpp);
            Ha[t][s] = h;
            S[(0 * BS + m0 + s) * HID + t] = sp;
            C[(0 * BS + m0 + s) * HID + t] = fpp;
        }
    }
    __syncthreads();
    fwd16(1, t, m0, Ha, Hb, W1, b1, S, C);  // h2 in Hb
    __syncthreads();
    fwd16(2, t, m0, Hb, Ha, W2, b2, S, C);  // h3 in Ha
    __syncthreads();
    // ---- layer 4 + start of backward ----
    {
        float acc[SPB1];
        #pragma unroll
        for (int s = 0; s < SPB1; ++s) acc[s] = b3[t];
        const float4* H4 = (const float4*)&Ha[0][0];
        #pragma unroll 4
        for (int i = 0; i < 256; ++i) {
            float w = W3[i * 256 + t];
            #pragma unroll
            for (int q = 0; q < 4; ++q) {
                float4 h = H4[i * 4 + q];
                acc[q * 4 + 0] += h.x * w; acc[q * 4 + 1] += h.y * w;
                acc[q * 4 + 2] += h.z * w; acc[q * 4 + 3] += h.w * w;
            }
        }
        float w4 = W4[t];
        #pragma unroll
        for (int s = 0; s < SPB1; ++s) {
            float h, sp, fpp;
            silu_derivs(acc[s], h, sp, fpp);
            Hb[t][s] = w4 * sp;                          // delta_a4
            C[(3 * BS + m0 + s) * HID + t] = w4 * fpp;   // c4 (final)
        }
    }
    __syncthreads();
    bwd16(2, t, m0, Hb, Ha, WT3, S, C);  // delta_a3 in Ha
    __syncthreads();
    bwd16(1, t, m0, Ha, Hb, WT2, S, C);  // delta_a2 in Hb
    __syncthreads();
    bwd16(0, t, m0, Hb, Ha, WT1, S, C);  // delta_a1 in Ha
    __syncthreads();
    // ---- gradient: g[k] = sum_i W0[k][i] * delta_a1[i] ----
    {
        const int k = t & 31;
        #pragma unroll
        for (int pass = 0; pass < 2; ++pass) {
            const int sh = (t >> 5) + 8 * pass;
            float acc = 0.0f;
            #pragma unroll 4
            for (int i = 0; i < 256; ++i) acc += WT0[i * 32 + k] * Ha[i][sh];
            if (k < 16) G[(m0 + sh) * 16 + k] = acc;
        }
    }
}

// ---------------- kernel 2: 8-wave 32x32 MFMA, PH=128 (2 phases/layer) ----------
// FROZEN from R15 (verified best: 609 us, MfmaUtil 27%, 65K bank conflicts).
#define RSW 136   // shorts per slot row (272 B, ≡4 dwords mod 32 banks)
#define STW 132   // floats per stg row (≡4 mod 32)

__global__ __launch_bounds__(512, 4) void k_stage2(
    const float* __restrict__ z,
    const float* __restrict__ W0,
    const ushort* __restrict__ WBT,
    const float* __restrict__ S, const float* __restrict__ C, const float* __restrict__ G,
    float* __restrict__ out)
{
    // slots: 0=ASh 1=ASl 2=ACh 3=ACl 4=TPh 5=TPl  (each 32 x RSW shorts)
    __shared__ __align__(16) ushort SMEM[6 * 32 * RSW];   // 52224 B
    __shared__ __align__(16) float stg[32 * STW];         // 16896 B
    __shared__ float HCl[32][16];
    __shared__ float Msys[16][17];
    __shared__ float vvs[16];

    const int t    = threadIdx.x;   // 0..511
    const int m    = blockIdx.x;
    const int lane = t & 63;
    const int w    = t >> 6;        // wave 0..7
    const int ln   = lane & 31;
    const int hf   = lane >> 5;
    const int er   = t >> 4;        // epilogue row 0..31
    const int ej   = (t & 15) * 8;  // epilogue col offset 0,8,..120

#define SLOT(a) (&SMEM[(a) * 32 * RSW])

    f32x16 Tacc;   // this wave's T columns (32w + ln), MFMA C-layout
    f32x16 Tnxt;
    f32x16 Dacc;
    #pragma unroll
    for (int r = 0; r < 16; ++r) { Tacc[r] = 0.0f; Tnxt[r] = 0.0f; Dacc[r] = 0.0f; }

    // prefetch C/S for (lay=0, p=0)
    float4 cc0, cc1, ss0, ss1;
    {
        const float* Cp = &C[(0 * BS + m) * HID + ej];
        const float* Sp = &S[(0 * BS + m) * HID + ej];
        cc0 = *(const float4*)Cp; cc1 = *(const float4*)(Cp + 4);
        ss0 = *(const float4*)Sp; ss1 = *(const float4*)(Sp + 4);
    }

    for (int lay = 0; lay < 4; ++lay) {
        for (int p = 0; p < 2; ++p) {
            // ---- issue next-phase C/S loads (consumed next phase) ----
            float4 cn0, cn1, sn0, sn1;
            const int nlay = (p < 1) ? lay : lay + 1;
            const int np   = (p < 1) ? 1 : 0;
            if (nlay < 4) {
                const float* Cp = &C[(nlay * BS + m) * HID + np * 128 + ej];
                cn0 = *(const float4*)Cp; cn1 = *(const float4*)(Cp + 4);
                if (nlay < 3) {
                    const float* Sp = &S[(nlay * BS + m) * HID + np * 128 + ej];
                    sn0 = *(const float4*)Sp; sn1 = *(const float4*)(Sp + 4);
                }
            }

            // ---------- epilogue: 512 threads x 8 elements ----------
            {
                float tv[8], tmp[8];
                if (lay == 0) {
                    const float* Wp = &W0[er * HID + p * 128 + ej];
                    *(float4*)&tv[0] = *(const float4*)Wp;
                    *(float4*)&tv[4] = *(const float4*)(Wp + 4);
                } else {
                    *(float4*)&tv[0] = *(const float4*)&stg[er * STW + ej];
                    *(float4*)&tv[4] = *(const float4*)&stg[er * STW + ej + 4];
                }
                uint4 H, L;
                tmp[0] = cc0.x * tv[0]; tmp[1] = cc0.y * tv[1];
                tmp[2] = cc0.z * tv[2]; tmp[3] = cc0.w * tv[3];
                tmp[4] = cc1.x * tv[4]; tmp[5] = cc1.y * tv[5];
                tmp[6] = cc1.z * tv[6]; tmp[7] = cc1.w * tv[7];
                split8v(tmp, H, L);
                *(uint4*)(SLOT(2) + er * RSW + ej) = H;
                *(uint4*)(SLOT(3) + er * RSW + ej) = L;
                if (lay < 3) {
                    tmp[0] = ss0.x * tv[0]; tmp[1] = ss0.y * tv[1];
                    tmp[2] = ss0.z * tv[2]; tmp[3] = ss0.w * tv[3];
                    tmp[4] = ss1.x * tv[4]; tmp[5] = ss1.y * tv[5];
                    tmp[6] = ss1.z * tv[6]; tmp[7] = ss1.w * tv[7];
                    split8v(tmp, H, L);
                    *(uint4*)(SLOT(0) + er * RSW + ej) = H;
                    *(uint4*)(SLOT(1) + er * RSW + ej) = L;
                }
                if (er >= 16) {   // waves 4..7 — wave-uniform branch
                    split8v(tv, H, L);
                    *(uint4*)(SLOT(4) + (er - 16) * RSW + ej) = H;
                    *(uint4*)(SLOT(5) + (er - 16) * RSW + ej) = L;
                }
            }
            __syncthreads();

            // ---------- contraction: ALL 8 waves, wave w takes K-chunk w ----------
            {
                const int ko = w * 16 + hf * 8;
                bf16x8 Bph = *(const bf16x8*)(SLOT(4) + ln * RSW + ko);
                bf16x8 Bpl = *(const bf16x8*)(SLOT(5) + ln * RSW + ko);
                bf16x8 Ah = *(const bf16x8*)(SLOT(2) + ln * RSW + ko);
                bf16x8 Al = *(const bf16x8*)(SLOT(3) + ln * RSW + ko);
                Dacc = MFMA32(Ah, Bph, MFMA32(Al, Bph, MFMA32(Ah, Bpl, Dacc)));
            }

            // ---------- GEMM: all 8 waves, wave w owns n-tile w, 8 K-chunks -------
            if (lay < 3) {
                #pragma unroll
                for (int ks = 0; ks < 8; ++ks) {
                    const int ko = ks * 16 + hf * 8;
                    const int kb = p * 8 + ks;
                    bf16x8 Ah = *(const bf16x8*)(SLOT(0) + ln * RSW + ko);
                    bf16x8 Al = *(const bf16x8*)(SLOT(1) + ln * RSW + ko);
                    bf16x8 Bh = *(const bf16x8*)&WBT[
                        (((lay * 2 + 0) * 128) + w * 16 + kb) * 512 + lane * 8];
                    bf16x8 Bl = *(const bf16x8*)&WBT[
                        (((lay * 2 + 1) * 128) + w * 16 + kb) * 512 + lane * 8];
                    Tnxt = MFMA32(Ah, Bh,
                           MFMA32(Al, Bh,
                           MFMA32(Ah, Bl, Tnxt)));
                }
            }

            // ---------- staging dump for the NEXT phase ----------
            if (p == 0) {
                if (lay > 0 && w >= 4) {   // next phase = cols 128..255 (Tacc)
                    #pragma unroll
                    for (int r = 0; r < 16; ++r) {
                        const int row = (r & 3) + 8 * (r >> 2) + 4 * hf;
                        stg[row * STW + (w - 4) * 32 + ln] = Tacc[r];
                    }
                }
            } else {
                if (lay < 3 && w < 4) {    // next layer cols 0..127 (Tnxt)
                    #pragma unroll
                    for (int r = 0; r < 16; ++r) {
                        const int row = (r & 3) + 8 * (r >> 2) + 4 * hf;
                        stg[row * STW + w * 32 + ln] = Tnxt[r];
                    }
                }
            }
            __syncthreads();

            // ---- rotate prefetched C/S ----
            if (nlay < 4) {
                cc0 = cn0; cc1 = cn1;
                if (nlay < 3) { ss0 = sn0; ss1 = sn1; }
            }
        } // p

        // ---------- layer end: Tacc <- Tnxt (registers only) ----------
        if (lay < 3) {
            Tacc = Tnxt;
            #pragma unroll
            for (int r = 0; r < 16; ++r) Tnxt[r] = 0.0f;
        }
    } // lay

    // ---------- reduce Hessian partials (overlay on SMEM; 16 valid cols) ----
    float* Dred = (float*)SMEM;   // [8][32][16] = 16 KB <= 52 KB
    {
        #pragma unroll
        for (int r = 0; r < 16; ++r) {
            const int row = (r & 3) + 8 * (r >> 2) + 4 * hf;
            if (ln < 16) Dred[(w * 32 + row) * 16 + ln] = Dacc[r];
        }
    }
    __syncthreads();

    // ---------- wave-0 reduce + solve ----------
    if (w == 0) {
        for (int idx = lane; idx < 512; idx += 64) {
            const int row = idx >> 4, j = idx & 15;
            float v = 0.0f;
            #pragma unroll
            for (int wv = 0; wv < 8; ++wv) v += Dred[(wv * 32 + row) * 16 + j];
            HCl[row][j] = v;
        }

        float* M = &Msys[0][0];   // [16][17]
        float vr = 0.0f;
        if (lane < 16) {
            vr = z[m * 32 + 16 + lane];
            vvs[lane] = vr;
        }
        if (lane < 16) {
            #pragma unroll
            for (int j = 0; j < 16; ++j)
                M[lane * 17 + j] = HCl[16 + lane][j] + (lane == j ? 0.2f : 0.0f);
            float r = G[m * 16 + lane];
            #pragma unroll
            for (int j = 0; j < 16; ++j)
                r -= HCl[j][lane] * vvs[j];
            M[lane * 17 + 16] = r;
        }
        // Gauss-Jordan with partial pivoting (wave-synchronous)
        for (int k2 = 0; k2 < 16; ++k2) {
            float val = (lane < 16 && lane >= k2) ? fabsf(M[lane * 17 + k2]) : -1.0f;
            int idx = lane;
            #pragma unroll
            for (int off = 8; off > 0; off >>= 1) {
                float ov = __shfl_xor(val, off, 64);
                int oi = __shfl_xor(idx, off, 64);
                if (ov > val) { val = ov; idx = oi; }
            }
            const int p2 = __shfl(idx, 0, 64);
            if (p2 != k2 && lane < 17) {
                float tmp = M[k2 * 17 + lane];
                M[k2 * 17 + lane] = M[p2 * 17 + lane];
                M[p2 * 17 + lane] = tmp;
            }
            if (lane < 16) {
                const float f = (lane == k2) ? 0.0f : M[lane * 17 + k2] / M[k2 * 17 + k2];
                #pragma unroll
                for (int j = 0; j < 17; ++j)
                    M[lane * 17 + j] -= f * M[k2 * 17 + j];
            }
        }
        if (lane < 16) {
            out[m * 32 + lane]      = vr;
            out[m * 32 + 16 + lane] = M[lane * 17 + 16] / M[lane * 17 + lane];
        }
    }
#undef SLOT
}

extern "C" void kernel_launch(void* const* d_in, const int* in_sizes, int n_in,
                              void* d_out, int out_size, void* d_ws, size_t ws_size,
                              hipStream_t stream) {
    const float* z  = (const float*)d_in[1];
    const float* W0 = (const float*)d_in[2];
    const float* b0 = (const float*)d_in[3];
    const float* W1 = (const float*)d_in[4];
    const float* b1 = (const float*)d_in[5];
    const float* W2 = (const float*)d_in[6];
    const float* b2 = (const float*)d_in[7];
    const float* W3 = (const float*)d_in[8];
    const float* b3 = (const float*)d_in[9];
    const float* W4 = (const float*)d_in[10];
    float* out = (float*)d_out;
    float* ws  = (float*)d_ws;

    float* WT1 = ws + WT1_OFF;
    float* WT2 = ws + WT2_OFF;
    float* WT3 = ws + WT3_OFF;
    float* WT0 = ws + WT0_OFF;
    float* S   = ws + S_OFF;
    float* C   = ws + C_OFF;
    float* G   = ws + G_OFF;
    const ushort* WBT = (const ushort*)(ws + WBT_OFF);

    k_transpose<<<dim3(256, 4), 256, 0, stream>>>(W0, W1, W2, W3, ws);
    k_stage1<<<BS / SPB1, 256, 0, stream>>>(z, W0, b0, W1, b1, W2, b2, W3, b3, W4,
                                            WT0, WT1, WT2, WT3, S, C, G);
    k_stage2<<<BS, 512, 0, stream>>>(z, W0, WBT, S, C, G, out);
}